// Round 8
// baseline (122.887 us; speedup 1.0000x reference)
//
#include <hip/hip_runtime.h>
#include <hip/hip_bf16.h>

#define BATCH 16384
#define DIM   512
#define UNITS 1024
// GAMMA = 0.5 folded into epilogue: out = exp(cross - 0.5*xsq - 0.5*musq)

typedef float v16f __attribute__((ext_vector_type(16)));

#define BPITCH 33
#define FPITCH 520   // fp8 LDS row pitch: 512+8 -> b64 frag reads at structural floor

// prep-B: mu [DIM][UNITS] fp32 -> B8f fragment-order fp8 + musq.
// B8f layout: byte ((ng*32 + kw)*64 + lane)*8, ng = n/32, kw = k/16.
//   Lane l holds B[kw*16 + (l>>5)*8 + 0..7][ng*32 + (l&31)].
__global__ __launch_bounds__(256)
void prep_b_kernel(const float* __restrict__ mu, unsigned char* __restrict__ B8f,
                   float* __restrict__ musq) {
    __shared__ __attribute__((aligned(16))) char smem[512 * BPITCH * 4 + 1024];
    float* lds = (float*)smem;                       // [512][BPITCH]
    float* red = (float*)(smem + 512 * BPITCH * 4);  // [32][8]
    const int t  = threadIdx.x;
    const int l  = t & 63, w = t >> 6;
    const int ln = l & 31, h = l >> 5;
    const int nb = blockIdx.x;
    const int n0 = nb * 32;
    const int col = t & 31, kg = t >> 5;
    float s = 0.f;
    for (int i = 0; i < 64; i++) {
        const int k = i * 8 + kg;
        float v = mu[(size_t)k * UNITS + n0 + col];
        s += v * v;
        lds[k * BPITCH + col] = v;
    }
    red[col * 8 + kg] = s;
    __syncthreads();
    if (t < 32) {
        float a = 0.f;
#pragma unroll
        for (int i = 0; i < 8; i++) a += red[t * 8 + i];
        musq[n0 + t] = a;
    }
#pragma unroll
    for (int j = 0; j < 8; j++) {
        const int kw = w * 8 + j;
        const float* p = lds + (kw * 16 + h * 8) * BPITCH + ln;
        float f[8];
#pragma unroll
        for (int i = 0; i < 8; i++) f[i] = p[i * BPITCH];
        int lo = __builtin_amdgcn_cvt_pk_fp8_f32(f[0], f[1], 0, false);
        lo     = __builtin_amdgcn_cvt_pk_fp8_f32(f[2], f[3], lo, true);
        int hi = __builtin_amdgcn_cvt_pk_fp8_f32(f[4], f[5], 0, false);
        hi     = __builtin_amdgcn_cvt_pk_fp8_f32(f[6], f[7], hi, true);
        *(int2*)(B8f + (((size_t)nb * 32 + kw) * 64 + l) * 8) = make_int2(lo, hi);
    }
}

// Fused convert+GEMM+RBF. 512 blocks x 512 threads (8 waves), 2 blocks/CU,
// one dispatch round. Block EXCLUSIVELY owns 32 M-rows x all 1024 N-cols,
// so the A fp32->fp8 fragment conversion is block-local (no prep-A kernel,
// no fp8 A round-trip through HBM/L2, one less dispatch gap).
// Stage 1: coalesced fp32 read of the 32x512 slice, in-register fp8 cvt,
//   row-major fp8 LDS tile (pitch 520), per-row ||x||^2 wave-reduced into
//   LDS. ONE barrier.
// Stage 2: barrier-free kw-loop: 1 ds_read_b64 A-frag (conflict-free) +
//   4 coalesced B-group loads (B8f = 512 KB, L2-resident on every XCD) +
//   4 MFMAs. acc = 4 x v16f = 64 VGPR -> 16 waves/CU.
// Epilogue: xsq from LDS, musq global, NT stores (don't evict B from L2).
__global__ __launch_bounds__(512, 4)
void rbf_fused_kernel(const float* __restrict__ in,
                      const unsigned char* __restrict__ B8f,
                      const float* __restrict__ musq,
                      float* __restrict__ out) {
    __shared__ __attribute__((aligned(16))) char smem[32 * FPITCH + 256];
    unsigned char* Af = (unsigned char*)smem;        // [32][FPITCH] fp8
    float* red = (float*)(smem + 32 * FPITCH);       // [32][2] partial xsq

    const int t  = threadIdx.x;
    const int l  = t & 63;
    const int w  = t >> 6;          // wave 0..7
    const int ln = l & 31;
    const int h  = l >> 5;
    const int m0 = blockIdx.x * 32;

    // ---- Stage 1: fp32 -> fp8 LDS tile + xsq ----
    const float4* src = (const float4*)(in + (size_t)m0 * DIM);
#pragma unroll
    for (int i = 0; i < 8; i++) {
        const int f = i * 512 + t;                   // float4 id 0..4095
        float4 v = src[f];
        float ss = v.x * v.x + v.y * v.y + v.z * v.z + v.w * v.w;
        int p = __builtin_amdgcn_cvt_pk_fp8_f32(v.x, v.y, 0, false);
        p     = __builtin_amdgcn_cvt_pk_fp8_f32(v.z, v.w, p, true);
        *(int*)(Af + (f >> 7) * FPITCH + (f & 127) * 4) = p;
        // all 64 lanes of this wave hold the SAME row (i*4 + w/2): wave-reduce
        for (int off = 32; off; off >>= 1) ss += __shfl_down(ss, off, 64);
        if (l == 0) red[(i * 4 + (w >> 1)) * 2 + (w & 1)] = ss;
    }
    __syncthreads();

    // ---- Stage 2: barrier-free MFMA loop ----
    const int n0 = w * 128;         // wave's 128 columns (4 groups of 32)
    const long* bptr = (const long*)B8f + (size_t)(n0 >> 5) * 2048 + l;
    const unsigned char* ap = Af + ln * FPITCH + h * 8;

    v16f acc[4];
#pragma unroll
    for (int g = 0; g < 4; g++) acc[g] = (v16f)0.f;

#pragma unroll 4
    for (int kw = 0; kw < 32; kw++) {
        long a  = *(const long*)(ap + kw * 16);      // ds_read_b64, 2-way = free
        long b0 = bptr[kw * 64];
        long b1 = bptr[2048 + kw * 64];
        long b2 = bptr[4096 + kw * 64];
        long b3 = bptr[6144 + kw * 64];
        acc[0] = __builtin_amdgcn_mfma_f32_32x32x16_fp8_fp8(a, b0, acc[0], 0, 0, 0);
        acc[1] = __builtin_amdgcn_mfma_f32_32x32x16_fp8_fp8(a, b1, acc[1], 0, 0, 0);
        acc[2] = __builtin_amdgcn_mfma_f32_32x32x16_fp8_fp8(a, b2, acc[2], 0, 0, 0);
        acc[3] = __builtin_amdgcn_mfma_f32_32x32x16_fp8_fp8(a, b3, acc[3], 0, 0, 0);
    }

    // ---- Epilogue. C/D layout (m74/m101, dtype-indep): col = l&31,
    // row = (reg&3) + 8*(reg>>2) + 4*(l>>5). ----
    const float xv = -0.5f * (red[ln * 2] + red[ln * 2 + 1]);  // lane ln: row ln
#pragma unroll
    for (int g = 0; g < 4; g++) {
        const int nc = n0 + g * 32;
        const float mb = -0.5f * musq[nc + ln];
#pragma unroll
        for (int r = 0; r < 16; r++) {
            const int rl = (r & 3) + 8 * (r >> 2) + 4 * h;
            const float xb = __shfl(xv, rl, 64);     // lane rl holds row rl
            float v = __expf(acc[g][r] + xb + mb);
            __builtin_nontemporal_store(
                v, out + (size_t)(m0 + rl) * UNITS + nc + ln);
        }
    }
}

extern "C" void kernel_launch(void* const* d_in, const int* in_sizes, int n_in,
                              void* d_out, int out_size, void* d_ws, size_t ws_size,
                              hipStream_t stream) {
    const float* inputs = (const float*)d_in[0];   // [16384, 512] fp32
    const float* mu     = (const float*)d_in[1];   // [512, 1024] fp32
    float* out = (float*)d_out;                    // [16384, 1024] fp32

    char* ws = (char*)d_ws;
    unsigned char* B8f = (unsigned char*)ws;                     // 512 KiB
    float* musq        = (float*)(ws + (size_t)UNITS * DIM);     // 4 KiB

    prep_b_kernel<<<UNITS / 32, 256, 0, stream>>>(mu, B8f, musq);
    rbf_fused_kernel<<<BATCH / 32, 512, 0, stream>>>(inputs, B8f, musq, out);
}

// Round 9
// 112.016 us; speedup vs baseline: 1.0970x; 1.0970x over previous
//
#include <hip/hip_runtime.h>
#include <hip/hip_bf16.h>

#define BATCH 16384
#define DIM   512
#define UNITS 1024
// GAMMA = 0.5 folded into epilogue: out = exp(cross - 0.5*xsq - 0.5*musq)

typedef float v16f __attribute__((ext_vector_type(16)));

#define APITCH 516   // fp32 LDS pitch (floats) for prep-A transpose reads
#define BPITCH 33

__device__ __forceinline__ void async_copy16(const void* g, void* l) {
    __builtin_amdgcn_global_load_lds(
        (const __attribute__((address_space(1))) void*)g,
        (__attribute__((address_space(3))) void*)l,
        16 /*bytes*/, 0 /*offset*/, 0 /*aux*/);
}

// Fragment-order prep (fp8 e4m3), xsq/musq on ORIGINAL fp32 values.
// A8f: byte ((chunk*32 + kw)*64 + lane)*8 — lane l holds
//   A[chunk*32 + (l&31)][kw*16 + (l>>5)*8 + 0..7].
// B8f: byte ((ng*32 + kw)*64 + lane)*8 — lane l holds
//   B[kw*16 + (l>>5)*8 + 0..7][ng*32 + (l&31)].
// Blocks 0..31: B path (dispatched first; latency-bound). Blocks 32..543:
// A path, chunk c = ((b-32)&7)*64 + ((b-32)>>3) so that chunk c is converted
// on XCD floor(c/64) — the SAME XCD whose GEMM blocks read it (L2-local).
__global__ __launch_bounds__(256)
void prep_kernel(const float* __restrict__ in, const float* __restrict__ mu,
                 unsigned char* __restrict__ A8f, unsigned char* __restrict__ B8f,
                 float* __restrict__ xsq, float* __restrict__ musq) {
    __shared__ __attribute__((aligned(16))) char smem[512 * BPITCH * 4 + 1024];
    const int t  = threadIdx.x;
    const int l  = t & 63, w = t >> 6;
    const int ln = l & 31, h = l >> 5;

    if (blockIdx.x >= UNITS / 32) {
        // ---- A path: one block per 32-row chunk, XCD-matched to the GEMM ----
        float* lds = (float*)smem;                       // [32][APITCH]
        float* red = (float*)(smem + 32 * APITCH * 4);   // [32][8]
        const int bb = blockIdx.x - UNITS / 32;
        const int c  = (bb & 7) * 64 + (bb >> 3);        // chunk 0..511
        const float4* src = (const float4*)(in + (size_t)c * 32 * DIM);
        float4* l4 = (float4*)lds;
#pragma unroll
        for (int i = 0; i < 16; i++) {
            const int f = i * 256 + t;                   // float4 id 0..4095
            l4[(f >> 7) * (APITCH / 4) + (f & 127)] = src[f];
        }
        __syncthreads();
        float s = 0.f;
#pragma unroll
        for (int j = 0; j < 8; j++) {
            const int kw = w * 8 + j;
            const float* p = lds + ln * APITCH + kw * 16 + h * 8;
            float4 f0 = *(const float4*)p;
            float4 f1 = *(const float4*)(p + 4);
            s += f0.x * f0.x + f0.y * f0.y + f0.z * f0.z + f0.w * f0.w
               + f1.x * f1.x + f1.y * f1.y + f1.z * f1.z + f1.w * f1.w;
            int lo = __builtin_amdgcn_cvt_pk_fp8_f32(f0.x, f0.y, 0, false);
            lo     = __builtin_amdgcn_cvt_pk_fp8_f32(f0.z, f0.w, lo, true);
            int hi = __builtin_amdgcn_cvt_pk_fp8_f32(f1.x, f1.y, 0, false);
            hi     = __builtin_amdgcn_cvt_pk_fp8_f32(f1.z, f1.w, hi, true);
            *(int2*)(A8f + (((size_t)c * 32 + kw) * 64 + l) * 8) = make_int2(lo, hi);
        }
        red[ln * 8 + w * 2 + h] = s;
        __syncthreads();
        if (t < 32) {
            float a = 0.f;
#pragma unroll
            for (int i = 0; i < 8; i++) a += red[t * 8 + i];
            xsq[c * 32 + t] = a;
        }
    } else {
        // ---- B path: one block per 32-column group ----
        float* lds = (float*)smem;                       // [512][BPITCH]
        float* red = (float*)(smem + 512 * BPITCH * 4);  // [32][8]
        const int nb = blockIdx.x;
        const int n0 = nb * 32;
        const int col = t & 31, kg = t >> 5;
        float s = 0.f;
        for (int i = 0; i < 64; i++) {
            const int k = i * 8 + kg;
            float v = mu[(size_t)k * UNITS + n0 + col];
            s += v * v;
            lds[k * BPITCH + col] = v;
        }
        red[col * 8 + kg] = s;
        __syncthreads();
        if (t < 32) {
            float a = 0.f;
#pragma unroll
            for (int i = 0; i < 8; i++) a += red[t * 8 + i];
            musq[n0 + t] = a;
        }
#pragma unroll
        for (int j = 0; j < 8; j++) {
            const int kw = w * 8 + j;
            const float* p = lds + (kw * 16 + h * 8) * BPITCH + ln;
            float f[8];
#pragma unroll
            for (int i = 0; i < 8; i++) f[i] = p[i * BPITCH];
            int lo = __builtin_amdgcn_cvt_pk_fp8_f32(f[0], f[1], 0, false);
            lo     = __builtin_amdgcn_cvt_pk_fp8_f32(f[2], f[3], lo, true);
            int hi = __builtin_amdgcn_cvt_pk_fp8_f32(f[4], f[5], 0, false);
            hi     = __builtin_amdgcn_cvt_pk_fp8_f32(f[6], f[7], hi, true);
            *(int2*)(B8f + (((size_t)nb * 32 + kw) * 64 + l) * 8) = make_int2(lo, hi);
        }
    }
}

// RBF GEMM, 256 blocks x 1024 threads (16 waves, 1 block/CU).
// Block tile 256M x 256N. B-tile = 128 KB of fragment-order B8f (contiguous)
// staged into LDS ONCE -> device B-read volume 32 MB (was 256 MB: the wall).
// A8f streamed from global, coalesced 512 B loads, L2-local to the XCD
// (grid mapping gives XCD x the m-tiles [x*8, x*8+8), matching prep-A's
// placement). ONE barrier; kw-loop is barrier-free: 2 A global + 2 B
// ds_read_b64 (lane-linear, conflict-free) + 4 MFMAs.
__global__ __launch_bounds__(1024, 4)
void rbf_gemm_kernel(const unsigned char* __restrict__ A8f,
                     const unsigned char* __restrict__ B8f,
                     const float* __restrict__ xsq,
                     const float* __restrict__ musq,
                     float* __restrict__ out) {
    __shared__ __attribute__((aligned(16))) unsigned char Bs[131072]; // 128 KB

    const int t  = threadIdx.x;
    const int l  = t & 63;
    const int w  = t >> 6;          // wave 0..15
    const int ln = l & 31;
    const int h  = l >> 5;

    const int b  = blockIdx.x;      // 0..255
    const int x  = b & 7;           // XCD (round-robin dispatch)
    const int j  = b >> 3;          // 0..31
    const int mt = x * 8 + (j & 7); // m-tile 0..63 (256 rows)
    const int nt = j >> 3;          // n-tile 0..3  (256 cols)
    const int m0 = mt * 256;
    const int n0 = nt * 256;
    const int wm = (w >> 2) * 64;   // wave row origin in tile
    const int wn = (w & 3) * 64;    // wave col origin in tile

    // ---- Stage B-tile (contiguous 128 KB of B8f) into LDS ----
    const unsigned char* bsrc = B8f + (size_t)n0 * 512;  // ng0*16384 = n0*512
#pragma unroll
    for (int i = 0; i < 8; i++) {
        const int c = i * 1024 + t;                      // 16B chunk 0..8191
        async_copy16(bsrc + c * 16, Bs + c * 16);
    }
    __syncthreads();

    // ---- Barrier-free MFMA loop ----
    const long* Af  = (const long*)A8f + (size_t)((m0 + wm) >> 5) * 2048 + l;
    const long* lbp = (const long*)Bs + (size_t)(wn >> 5) * 2048 + l;

    v16f acc[2][2];
#pragma unroll
    for (int c = 0; c < 2; c++)
#pragma unroll
        for (int g = 0; g < 2; g++) acc[c][g] = (v16f)0.f;

#pragma unroll 4
    for (int kw = 0; kw < 32; kw++) {
        long a0 = Af[kw * 64];
        long a1 = Af[2048 + kw * 64];
        long b0 = lbp[kw * 64];
        long b1 = lbp[2048 + kw * 64];
        acc[0][0] = __builtin_amdgcn_mfma_f32_32x32x16_fp8_fp8(a0, b0, acc[0][0], 0, 0, 0);
        acc[0][1] = __builtin_amdgcn_mfma_f32_32x32x16_fp8_fp8(a0, b1, acc[0][1], 0, 0, 0);
        acc[1][0] = __builtin_amdgcn_mfma_f32_32x32x16_fp8_fp8(a1, b0, acc[1][0], 0, 0, 0);
        acc[1][1] = __builtin_amdgcn_mfma_f32_32x32x16_fp8_fp8(a1, b1, acc[1][1], 0, 0, 0);
    }

    // ---- Epilogue. C/D layout (m74/m101, dtype-indep): col = l&31,
    // row = (reg&3) + 8*(reg>>2) + 4*(l>>5). ----
#pragma unroll
    for (int c = 0; c < 2; c++) {
        const int mc = m0 + wm + c * 32;
        const float xv = -0.5f * xsq[mc + ln];     // lane ln holds row mc+ln
#pragma unroll
        for (int g = 0; g < 2; g++) {
            const int nc = n0 + wn + g * 32;
            const float mb = -0.5f * musq[nc + ln];
#pragma unroll
            for (int r = 0; r < 16; r++) {
                const int rl = (r & 3) + 8 * (r >> 2) + 4 * h;
                const float xb = __shfl(xv, rl, 64);
                float v = __expf(acc[c][g][r] + xb + mb);
                __builtin_nontemporal_store(
                    v, out + (size_t)(mc + rl) * UNITS + nc + ln);
            }
        }
    }
}

extern "C" void kernel_launch(void* const* d_in, const int* in_sizes, int n_in,
                              void* d_out, int out_size, void* d_ws, size_t ws_size,
                              hipStream_t stream) {
    const float* inputs = (const float*)d_in[0];   // [16384, 512] fp32
    const float* mu     = (const float*)d_in[1];   // [512, 1024] fp32
    float* out = (float*)d_out;                    // [16384, 1024] fp32

    char* ws = (char*)d_ws;
    unsigned char* A8f = (unsigned char*)ws;                           // 8 MiB
    unsigned char* B8f = (unsigned char*)(ws + (size_t)BATCH * DIM);   // 512 KiB
    float* xsq  = (float*)(ws + (size_t)BATCH * DIM + (size_t)UNITS * DIM);
    float* musq = xsq + BATCH;

    prep_kernel<<<UNITS / 32 + BATCH / 32, 256, 0, stream>>>(
        inputs, mu, A8f, B8f, xsq, musq);
    rbf_gemm_kernel<<<256, 1024, 0, stream>>>(A8f, B8f, xsq, musq, out);
}